// Round 8
// baseline (368.181 us; speedup 1.0000x reference)
//
#include <hip/hip_runtime.h>
#include <hip/hip_bf16.h>

#define BB 32
#define HH 56
#define WW 56
#define CC 256
#define NPIX (BB*HH*WW)   // 100352
#define EPS 1e-5f

typedef short bf16x8 __attribute__((ext_vector_type(8)));   // 8 bf16 = 4 VGPRs
typedef float f32x4  __attribute__((ext_vector_type(4)));

__device__ __forceinline__ unsigned short f2bf(float f) {
    __hip_bfloat16 h = __float2bfloat16(f);
    return *reinterpret_cast<unsigned short*>(&h);
}

// ws layout:
//   float stats[512]        : byte 0      (sum[256], sumsq[256])
//   bf16  yg[16][NPIX][16]  : byte 4096               (51.4 MB, gp-major y)
//   bf16  wT[256][80]       : byte 4096+51380224      (40 KB, conv-ready wgt)
//
// xg intermediate ELIMINATED this round: k1 now reads x directly with an
// all-channel 8x8-patch decomposition (1KB-contiguous record reads, the
// k_pre pattern), converting in-kernel. Saves xg's 51MB write + 66MB read.
// Occupancy was proven NOT the k1 lever (rounds 1,7 both neutral).

// Init: zero stats + build wT (weights transposed to [gp*16+n][tap][ci],
// bf16) so k1 reads each MFMA A-fragment as ONE b128 load.
__global__ __launch_bounds__(256) void k_init(
    const float* __restrict__ wgt, unsigned short* __restrict__ wT,
    float* __restrict__ stats)
{
    const int t = threadIdx.x;
    if (t < 128)
        *(float4*)(stats + t*4) = make_float4(0.f, 0.f, 0.f, 0.f);
    const int cw = t;                   // gp*16 + n
    unsigned short* dst = wT + (size_t)cw*80;
    #pragma unroll
    for (int tap = 0; tap < 9; ++tap) {
        ushort4 s4;
        s4.x = f2bf(wgt[(tap*8+0)*CC + cw]);
        s4.y = f2bf(wgt[(tap*8+1)*CC + cw]);
        s4.z = f2bf(wgt[(tap*8+2)*CC + cw]);
        s4.w = f2bf(wgt[(tap*8+3)*CC + cw]);
        *(ushort4*)(dst + tap*8) = s4;
        s4.x = f2bf(wgt[(tap*8+4)*CC + cw]);
        s4.y = f2bf(wgt[(tap*8+5)*CC + cw]);
        s4.z = f2bf(wgt[(tap*8+6)*CC + cw]);
        s4.w = f2bf(wgt[(tap*8+7)*CC + cw]);
        *(ushort4*)(dst + tap*8 + 4) = s4;
    }
}

// Grouped conv via bf16 MFMA, direct from x.
// Block = one 8x8 pixel patch x ALL 256 channels (grid 49 patches x 32 b).
// Stage: 100 records (10x10 halo) x 1KB contiguous -> cvt bf16 -> 16
// per-gp LDS subtiles [100 px][16ch], stride 1608 shorts (3216B: 16B-
// aligned b128 reads, subtile bank offset 4 -> ~4-way conflicts, benign).
// Compute: wave w owns gps 4w..4w+3; per gp the round-1-verified block-
// diagonal scheme: K packed [g0 taps+pad][g1 taps+pad] = 160 -> 5 x
// mfma_f32_16x16x32_bf16; 4 pixel-tiles (2 rows x 8 cols) per gp.
// C layout: lane holds ch gp*16+q*4+0..3 of pixel m -> ushort4 to gp-major
// yg (256B-contiguous per 8-px row). Stats: shuffle over m + global atomic.
__global__ __launch_bounds__(256, 3) void k1_conv(
    const float* __restrict__ x, const unsigned short* __restrict__ wT,
    __hip_bfloat16* __restrict__ yg, float* __restrict__ stats)
{
    __shared__ unsigned short xt[16*1608];    // 51,456 B
    const int patch = blockIdx.x;             // 0..48
    const int b     = blockIdx.y;
    const int t     = threadIdx.x;
    const int ph    = patch / 7, pw = patch - ph*7;
    const int h0    = ph * 8,    w0 = pw * 8;

    // ---- stage: 100 pixel records, 1KB contiguous each (one record/wave/round)
    #pragma unroll 5
    for (int r = 0; r < 25; ++r) {
        const int id  = r*256 + t;            // 0..6399
        const int rec = id >> 6;              // 0..99
        const int c4  = id & 63;              // float4 chunk within record
        const int pr_ = rec / 10;             // tile row 0..9
        const int pc_ = rec - pr_*10;         // tile col 0..9
        const int hh  = h0 - 1 + pr_;
        const int wc  = w0 - 1 + pc_;
        float4 v = make_float4(0.f, 0.f, 0.f, 0.f);
        if ((unsigned)hh < HH && (unsigned)wc < WW)
            v = *(const float4*)(x + ((size_t)(b*HH + hh)*WW + wc)*CC + c4*4);
        ushort4 s;
        s.x = f2bf(v.x); s.y = f2bf(v.y); s.z = f2bf(v.z); s.w = f2bf(v.w);
        *(ushort4*)(xt + (c4>>2)*1608 + rec*16 + (c4&3)*4) = s;
    }

    const int lane = t & 63;
    const int w    = t >> 6;                  // wave 0..3
    const int m    = lane & 15;               // A row (out-ch) == B col (pixel)
    const int q    = lane >> 4;               // K-octet
    const int colb = m & 7;                   // pixel col within patch
    const int prow = m >> 3;                  // pixel row within 2-row tile

    // B-fragment LDS offsets per K-step (octet -> tap,g), subtile-relative
    int aoff[5];
    #pragma unroll
    for (int s = 0; s < 5; ++s) {
        int o  = s*4 + q;
        int g  = (o >= 10);
        int tp = o - g*10;
        if (tp == 9) tp = 0;                  // pad octet: wfrag is zero
        int dh = tp / 3, dw = tp - dh*3;
        aoff[s] = ((prow + dh)*10 + colb + dw)*16 + g*8;
    }

    __syncthreads();

    #pragma unroll
    for (int gi = 0; gi < 4; ++gi) {
        const int gp = w*4 + gi;              // group pair 0..15
        // A-fragments: one b128 per K-step from wT (L2-hit broadcast)
        const unsigned short* wrow = wT + (size_t)(gp*16 + m)*80;
        bf16x8 wfrag[5];
        #pragma unroll
        for (int s = 0; s < 5; ++s) {
            const int o   = s*4 + q;
            const int g   = (o >= 10);
            const int tap = o - g*10;
            bf16x8 f = {0,0,0,0,0,0,0,0};
            if (tap < 9 && (m >> 3) == g)
                f = *(const bf16x8*)(wrow + tap*8);
            wfrag[s] = f;
        }
        const int sbase = gp*1608;
        float lsum[4] = {0.f,0.f,0.f,0.f};
        float lsq[4]  = {0.f,0.f,0.f,0.f};

        #pragma unroll
        for (int pt = 0; pt < 4; ++pt) {      // 4 pixel-tiles (2 rows x 8 cols)
            f32x4 acc = {0.f,0.f,0.f,0.f};
            #pragma unroll
            for (int s = 0; s < 5; ++s) {
                bf16x8 af = *(const bf16x8*)(xt + sbase + aoff[s] + pt*320);
                acc = __builtin_amdgcn_mfma_f32_16x16x32_bf16(wfrag[s], af, acc, 0, 0, 0);
            }
            // lane holds ch gp*16+q*4+0..3 of pixel (h0+pt*2+prow, w0+colb)
            const int pix = (b*HH + h0 + pt*2 + prow)*WW + w0 + colb;
            ushort4 st;
            st.x = f2bf(acc[0]); st.y = f2bf(acc[1]);
            st.z = f2bf(acc[2]); st.w = f2bf(acc[3]);
            *(ushort4*)(yg + ((size_t)gp*NPIX + pix)*16 + q*4) = st;
            #pragma unroll
            for (int i = 0; i < 4; ++i) {
                lsum[i] += acc[i];
                lsq[i]  += acc[i]*acc[i];
            }
        }
        // reduce over the 16 pixels (m bits) sharing this channel quad
        #pragma unroll
        for (int d = 8; d >= 1; d >>= 1) {
            #pragma unroll
            for (int i = 0; i < 4; ++i) {
                lsum[i] += __shfl_xor(lsum[i], d);
                lsq[i]  += __shfl_xor(lsq[i],  d);
            }
        }
        if (m == 0) {
            #pragma unroll
            for (int i = 0; i < 4; ++i) {
                atomicAdd(&stats[gp*16 + q*4 + i],       lsum[i]);
                atomicAdd(&stats[256 + gp*16 + q*4 + i], lsq[i]);
            }
        }
    }
}

// Normalize+ReLU with the gp-major -> pixel-major transpose via LDS.
// Reads yg in 1KB-contiguous chunks per gp slice; writes out f32 NHWC
// 1KB-contiguous per pixel. scale/shift computed inline from stats.
__global__ __launch_bounds__(256) void k3_norm(
    const __hip_bfloat16* __restrict__ yg, const float* __restrict__ stats,
    const float* __restrict__ gamma, const float* __restrict__ beta,
    float* __restrict__ out)
{
    __shared__ unsigned short lx[32*260];   // 32 pixels x 256ch (+pad) = 16.6 KB
    const int t  = threadIdx.x;
    const int P0 = blockIdx.x * 32;

    // ---- load 16 gp slices x 32 pixels (32B each) into LDS pixel-major
    #pragma unroll
    for (int r = 0; r < 2; ++r) {
        const int id = r*256 + t;           // gp = id>>5, pl = id&31
        const int g  = id >> 5;
        const int pl = id & 31;
        const __hip_bfloat16* src = yg + ((size_t)g*NPIX + P0 + pl)*16;
        uint4 v0 = *(const uint4*)(src);
        uint4 v1 = *(const uint4*)(src + 8);
        *(uint4*)(lx + pl*260 + g*16)     = v0;
        *(uint4*)(lx + pl*260 + g*16 + 8) = v1;
    }

    // ---- per-thread scale/shift for its channel octet (overlaps LDS fill)
    const int oct = t & 31;               // channel octet
    const int pr  = t >> 5;               // pixel sub-index 0..7
    const int c0  = oct * 8;
    const float inv_n = 1.f / (float)NPIX;
    float sc[8], sh[8];
    #pragma unroll
    for (int i = 0; i < 8; ++i) {
        float mean = stats[c0+i] * inv_n;
        float var  = stats[256+c0+i] * inv_n - mean*mean;
        float s    = gamma[c0+i] * rsqrtf(var + EPS);
        sc[i] = s;
        sh[i] = beta[c0+i] - mean * s;    // conv bias cancels under BN
    }
    __syncthreads();

    #pragma unroll
    for (int i = 0; i < 4; ++i) {
        const int pl = pr + i*8;
        ushort4 a = *(const ushort4*)(lx + pl*260 + c0);
        ushort4 c = *(const ushort4*)(lx + pl*260 + c0 + 4);
        float f0 = __uint_as_float((unsigned)a.x << 16);
        float f1 = __uint_as_float((unsigned)a.y << 16);
        float f2 = __uint_as_float((unsigned)a.z << 16);
        float f3 = __uint_as_float((unsigned)a.w << 16);
        float f4 = __uint_as_float((unsigned)c.x << 16);
        float f5 = __uint_as_float((unsigned)c.y << 16);
        float f6 = __uint_as_float((unsigned)c.z << 16);
        float f7 = __uint_as_float((unsigned)c.w << 16);

        float4 o0, o1;
        o0.x = fmaxf(0.f, f0 * sc[0] + sh[0]);
        o0.y = fmaxf(0.f, f1 * sc[1] + sh[1]);
        o0.z = fmaxf(0.f, f2 * sc[2] + sh[2]);
        o0.w = fmaxf(0.f, f3 * sc[3] + sh[3]);
        o1.x = fmaxf(0.f, f4 * sc[4] + sh[4]);
        o1.y = fmaxf(0.f, f5 * sc[5] + sh[5]);
        o1.z = fmaxf(0.f, f6 * sc[6] + sh[6]);
        o1.w = fmaxf(0.f, f7 * sc[7] + sh[7]);

        float* dst = out + (size_t)(P0 + pl)*CC + c0;
        *(float4*)(dst)     = o0;
        *(float4*)(dst + 4) = o1;
    }
}

extern "C" void kernel_launch(void* const* d_in, const int* in_sizes, int n_in,
                              void* d_out, int out_size, void* d_ws, size_t ws_size,
                              hipStream_t stream) {
    const float* x     = (const float*)d_in[0];
    const float* wgt   = (const float*)d_in[1];
    // d_in[2] = conv bias: cancels exactly under BN mean-subtraction -- unused
    const float* gamma = (const float*)d_in[3];
    const float* beta  = (const float*)d_in[4];
    float* out = (float*)d_out;

    float* stats = (float*)d_ws;                                   // 512 floats
    __hip_bfloat16* yg = (__hip_bfloat16*)((char*)d_ws + 4096);    // 51.4 MB
    unsigned short* wT = (unsigned short*)((char*)d_ws + 4096 + (size_t)NPIX*CC*2);

    k_init<<<1, 256, 0, stream>>>(wgt, wT, stats);
    k1_conv<<<dim3(49, BB), 256, 0, stream>>>(x, wT, yg, stats);
    k3_norm<<<NPIX/32, 256, 0, stream>>>(yg, stats, gamma, beta, out);
}

// Round 9
// 249.467 us; speedup vs baseline: 1.4759x; 1.4759x over previous
//
#include <hip/hip_runtime.h>
#include <hip/hip_bf16.h>

#define BB 32
#define HH 56
#define WW 56
#define CC 256
#define NPIX (BB*HH*WW)   // 100352
#define EPS 1e-5f
#define NCPY 16           // stat copies (contention split)

typedef short bf16x8 __attribute__((ext_vector_type(8)));   // 8 bf16 = 4 VGPRs
typedef float f32x4  __attribute__((ext_vector_type(4)));

__device__ __forceinline__ unsigned short f2bf(float f) {
    __hip_bfloat16 h = __float2bfloat16(f);
    return *reinterpret_cast<unsigned short*>(&h);
}

// ws layout:
//   float stats[16][512]    : byte 0      (16 copies: sum[256],sumsq[256])
//   bf16  yg[16][NPIX][16]  : byte 32768             (51.4 MB, gp-major y)
//   bf16  wT[256][80]       : byte 32768+51380224    (40 KB, conv-ready wgt)
//
// Round-8 post-mortem: direct-from-x patch decomposition cut k1 traffic to
// 137MB as designed, but per-channel stats atomics went from 224 to 784
// serialized same-line hits per address (all 1568 blocks hit all 512
// addresses) -> ~150us atomic pipeline serialization (k1 203us, all pipes
// idle). Fix: 16-way stat copies (98 hits/addr) + k3 inline re-reduce.

// Init: zero 16 stat copies + build wT ([gp*16+n][tap][ci] bf16) so k1
// reads each MFMA A-fragment as ONE b128 load.
__global__ __launch_bounds__(256) void k_init(
    const float* __restrict__ wgt, unsigned short* __restrict__ wT,
    float* __restrict__ stats)
{
    const int t = threadIdx.x;
    #pragma unroll
    for (int r = 0; r < NCPY*512/1024; ++r)     // 8192 floats
        *(float4*)(stats + (r*256 + t)*4) = make_float4(0.f, 0.f, 0.f, 0.f);
    const int cw = t;                   // gp*16 + n
    unsigned short* dst = wT + (size_t)cw*80;
    #pragma unroll
    for (int tap = 0; tap < 9; ++tap) {
        ushort4 s4;
        s4.x = f2bf(wgt[(tap*8+0)*CC + cw]);
        s4.y = f2bf(wgt[(tap*8+1)*CC + cw]);
        s4.z = f2bf(wgt[(tap*8+2)*CC + cw]);
        s4.w = f2bf(wgt[(tap*8+3)*CC + cw]);
        *(ushort4*)(dst + tap*8) = s4;
        s4.x = f2bf(wgt[(tap*8+4)*CC + cw]);
        s4.y = f2bf(wgt[(tap*8+5)*CC + cw]);
        s4.z = f2bf(wgt[(tap*8+6)*CC + cw]);
        s4.w = f2bf(wgt[(tap*8+7)*CC + cw]);
        *(ushort4*)(dst + tap*8 + 4) = s4;
    }
}

// Grouped conv via bf16 MFMA, direct from x.
// Block = one 8x8 pixel patch x ALL 256 channels (grid 49 patches x 32 b).
// Stage: 100 records (10x10 halo) x 1KB contiguous -> cvt bf16 -> 16
// per-gp LDS subtiles [100 px][16ch], stride 1608 shorts; pixel-XOR bank
// swizzle (byte ^= (pix&4)<<2, same on write and read) -> b128 MFMA reads
// are 2-way (free).
// Compute: wave w owns gps 4w..4w+3; block-diagonal K=160 scheme, 5 x
// mfma_f32_16x16x32_bf16 per pixel-tile; C: lane holds ch gp*16+q*4+0..3
// of pixel m -> ushort4 to gp-major yg (256B-contiguous per 8-px row).
// Stats: shuffle over m + atomics into copy (bidx+bidy)&15.
__global__ __launch_bounds__(256, 3) void k1_conv(
    const float* __restrict__ x, const unsigned short* __restrict__ wT,
    __hip_bfloat16* __restrict__ yg, float* __restrict__ stats)
{
    __shared__ unsigned short xt[16*1608];    // 51,456 B
    const int patch = blockIdx.x;             // 0..48
    const int b     = blockIdx.y;
    const int t     = threadIdx.x;
    const int ph    = patch / 7, pw = patch - ph*7;
    const int h0    = ph * 8,    w0 = pw * 8;
    float* statc = stats + ((blockIdx.x + blockIdx.y) & (NCPY-1)) * 512;

    // ---- stage: 100 pixel records, 1KB contiguous each (one record/wave/round)
    #pragma unroll 5
    for (int r = 0; r < 25; ++r) {
        const int id  = r*256 + t;            // 0..6399
        const int rec = id >> 6;              // 0..99
        const int c4  = id & 63;              // float4 chunk within record
        const int pr_ = rec / 10;             // tile row 0..9
        const int pc_ = rec - pr_*10;         // tile col 0..9
        const int hh  = h0 - 1 + pr_;
        const int wc  = w0 - 1 + pc_;
        float4 v = make_float4(0.f, 0.f, 0.f, 0.f);
        if ((unsigned)hh < HH && (unsigned)wc < WW)
            v = *(const float4*)(x + ((size_t)(b*HH + hh)*WW + wc)*CC + c4*4);
        ushort4 s;
        s.x = f2bf(v.x); s.y = f2bf(v.y); s.z = f2bf(v.z); s.w = f2bf(v.w);
        const int so = (rec*16 + (c4&3)*4) ^ ((rec & 4) << 1);   // pixel-XOR swizzle
        *(ushort4*)(xt + (c4>>2)*1608 + so) = s;
    }

    const int lane = t & 63;
    const int w    = t >> 6;                  // wave 0..3
    const int m    = lane & 15;               // A row (out-ch) == B col (pixel)
    const int q    = lane >> 4;               // K-octet
    const int colb = m & 7;                   // pixel col within patch
    const int prow = m >> 3;                  // pixel row within 2-row tile

    // B-fragment pixel bases + group-half offsets per K-step (octet -> tap,g)
    int pbase[5], goff[5];
    #pragma unroll
    for (int s = 0; s < 5; ++s) {
        int o  = s*4 + q;
        int g  = (o >= 10);
        int tp = o - g*10;
        if (tp == 9) tp = 0;                  // pad octet: wfrag is zero
        int dh = tp / 3, dw = tp - dh*3;
        pbase[s] = (prow + dh)*10 + colb + dw;
        goff[s]  = g*8;
    }

    __syncthreads();

    #pragma unroll
    for (int gi = 0; gi < 4; ++gi) {
        const int gp = w*4 + gi;              // group pair 0..15
        // A-fragments: one b128 per K-step from wT (L2-hit broadcast)
        const unsigned short* wrow = wT + (size_t)(gp*16 + m)*80;
        bf16x8 wfrag[5];
        #pragma unroll
        for (int s = 0; s < 5; ++s) {
            const int o   = s*4 + q;
            const int g   = (o >= 10);
            const int tap = o - g*10;
            bf16x8 f = {0,0,0,0,0,0,0,0};
            if (tap < 9 && (m >> 3) == g)
                f = *(const bf16x8*)(wrow + tap*8);
            wfrag[s] = f;
        }
        const int sbase = gp*1608;
        float lsum[4] = {0.f,0.f,0.f,0.f};
        float lsq[4]  = {0.f,0.f,0.f,0.f};

        #pragma unroll
        for (int pt = 0; pt < 4; ++pt) {      // 4 pixel-tiles (2 rows x 8 cols)
            f32x4 acc = {0.f,0.f,0.f,0.f};
            #pragma unroll
            for (int s = 0; s < 5; ++s) {
                const int p  = pbase[s] + pt*20;                    // pixel idx
                const int so = (p*16 + goff[s]) ^ ((p & 4) << 1);   // swizzled
                bf16x8 af = *(const bf16x8*)(xt + sbase + so);
                acc = __builtin_amdgcn_mfma_f32_16x16x32_bf16(wfrag[s], af, acc, 0, 0, 0);
            }
            // lane holds ch gp*16+q*4+0..3 of pixel (h0+pt*2+prow, w0+colb)
            const int pix = (b*HH + h0 + pt*2 + prow)*WW + w0 + colb;
            ushort4 st;
            st.x = f2bf(acc[0]); st.y = f2bf(acc[1]);
            st.z = f2bf(acc[2]); st.w = f2bf(acc[3]);
            *(ushort4*)(yg + ((size_t)gp*NPIX + pix)*16 + q*4) = st;
            #pragma unroll
            for (int i = 0; i < 4; ++i) {
                lsum[i] += acc[i];
                lsq[i]  += acc[i]*acc[i];
            }
        }
        // reduce over the 16 pixels (m bits) sharing this channel quad
        #pragma unroll
        for (int d = 8; d >= 1; d >>= 1) {
            #pragma unroll
            for (int i = 0; i < 4; ++i) {
                lsum[i] += __shfl_xor(lsum[i], d);
                lsq[i]  += __shfl_xor(lsq[i],  d);
            }
        }
        if (m == 0) {
            #pragma unroll
            for (int i = 0; i < 4; ++i) {
                atomicAdd(&statc[gp*16 + q*4 + i],       lsum[i]);
                atomicAdd(&statc[256 + gp*16 + q*4 + i], lsq[i]);
            }
        }
    }
}

// Normalize+ReLU with the gp-major -> pixel-major transpose via LDS.
// Reads yg in 1KB-contiguous chunks per gp slice; writes out f32 NHWC
// 1KB-contiguous per pixel. Re-reduces the 16 stat copies inline (L2-hot)
// into an LDS scale/shift table, then applies per channel octet.
__global__ __launch_bounds__(256) void k3_norm(
    const __hip_bfloat16* __restrict__ yg, const float* __restrict__ stats,
    const float* __restrict__ gamma, const float* __restrict__ beta,
    float* __restrict__ out)
{
    __shared__ unsigned short lx[32*260];   // 32 pixels x 256ch (+pad) = 16.6 KB
    __shared__ float scl[256], shl[256];
    const int t  = threadIdx.x;
    const int P0 = blockIdx.x * 32;

    // ---- load 16 gp slices x 32 pixels (32B each) into LDS pixel-major
    #pragma unroll
    for (int r = 0; r < 2; ++r) {
        const int id = r*256 + t;           // gp = id>>5, pl = id&31
        const int g  = id >> 5;
        const int pl = id & 31;
        const __hip_bfloat16* src = yg + ((size_t)g*NPIX + P0 + pl)*16;
        uint4 v0 = *(const uint4*)(src);
        uint4 v1 = *(const uint4*)(src + 8);
        *(uint4*)(lx + pl*260 + g*16)     = v0;
        *(uint4*)(lx + pl*260 + g*16 + 8) = v1;
    }

    // ---- channel t: reduce 16 stat copies, compute scale/shift (overlaps fill)
    {
        float s = 0.f, s2 = 0.f;
        #pragma unroll
        for (int c = 0; c < NCPY; ++c) {
            s  += stats[c*512 + t];
            s2 += stats[c*512 + 256 + t];
        }
        const float inv_n = 1.f / (float)NPIX;
        float mean = s * inv_n;
        float var  = s2 * inv_n - mean*mean;
        float sc_  = gamma[t] * rsqrtf(var + EPS);
        scl[t] = sc_;
        shl[t] = beta[t] - mean * sc_;    // conv bias cancels under BN
    }
    __syncthreads();

    const int oct = t & 31;               // channel octet
    const int pr  = t >> 5;               // pixel sub-index 0..7
    const int c0  = oct * 8;
    float sc[8], sh[8];
    #pragma unroll
    for (int i = 0; i < 8; ++i) { sc[i] = scl[c0+i]; sh[i] = shl[c0+i]; }

    #pragma unroll
    for (int i = 0; i < 4; ++i) {
        const int pl = pr + i*8;
        ushort4 a = *(const ushort4*)(lx + pl*260 + c0);
        ushort4 c = *(const ushort4*)(lx + pl*260 + c0 + 4);
        float f0 = __uint_as_float((unsigned)a.x << 16);
        float f1 = __uint_as_float((unsigned)a.y << 16);
        float f2 = __uint_as_float((unsigned)a.z << 16);
        float f3 = __uint_as_float((unsigned)a.w << 16);
        float f4 = __uint_as_float((unsigned)c.x << 16);
        float f5 = __uint_as_float((unsigned)c.y << 16);
        float f6 = __uint_as_float((unsigned)c.z << 16);
        float f7 = __uint_as_float((unsigned)c.w << 16);

        float4 o0, o1;
        o0.x = fmaxf(0.f, f0 * sc[0] + sh[0]);
        o0.y = fmaxf(0.f, f1 * sc[1] + sh[1]);
        o0.z = fmaxf(0.f, f2 * sc[2] + sh[2]);
        o0.w = fmaxf(0.f, f3 * sc[3] + sh[3]);
        o1.x = fmaxf(0.f, f4 * sc[4] + sh[4]);
        o1.y = fmaxf(0.f, f5 * sc[5] + sh[5]);
        o1.z = fmaxf(0.f, f6 * sc[6] + sh[6]);
        o1.w = fmaxf(0.f, f7 * sc[7] + sh[7]);

        float* dst = out + (size_t)(P0 + pl)*CC + c0;
        *(float4*)(dst)     = o0;
        *(float4*)(dst + 4) = o1;
    }
}

extern "C" void kernel_launch(void* const* d_in, const int* in_sizes, int n_in,
                              void* d_out, int out_size, void* d_ws, size_t ws_size,
                              hipStream_t stream) {
    const float* x     = (const float*)d_in[0];
    const float* wgt   = (const float*)d_in[1];
    // d_in[2] = conv bias: cancels exactly under BN mean-subtraction -- unused
    const float* gamma = (const float*)d_in[3];
    const float* beta  = (const float*)d_in[4];
    float* out = (float*)d_out;

    float* stats = (float*)d_ws;                                    // 16x512 f32
    __hip_bfloat16* yg = (__hip_bfloat16*)((char*)d_ws + 32768);    // 51.4 MB
    unsigned short* wT = (unsigned short*)((char*)d_ws + 32768 + (size_t)NPIX*CC*2);

    k_init<<<1, 256, 0, stream>>>(wgt, wT, stats);
    k1_conv<<<dim3(49, BB), 256, 0, stream>>>(x, wT, yg, stats);
    k3_norm<<<NPIX/32, 256, 0, stream>>>(yg, stats, gamma, beta, out);
}